// Round 4
// baseline (304.453 us; speedup 1.0000x reference)
//
#include <hip/hip_runtime.h>
#include <hip/hip_bf16.h>
#include <stdint.h>

#define DEV static __device__ __forceinline__

typedef __attribute__((ext_vector_type(8))) short bf16x8;
typedef __attribute__((ext_vector_type(4))) float f32x4;
typedef unsigned int u32;

static constexpr int T = 4096;
static constexpr int BATCH = 8;
static constexpr int DM = 1024;            // d_model = nhead*d_head
static constexpr int M1 = BATCH * T;       // 32768 rows into GEMM1
static constexpr int M2 = BATCH * (T + 1); // 32776 rows into GEMM2
static constexpr int M2P = 129 * 256;      // 33024 padded rows for S (256-tile)
static constexpr int NCH = 64;             // time chunks for scan
static constexpr int CL = T / NCH;         // 64 steps per chunk
static constexpr int NT = 32;              // K tiles (BK=32, K=1024)

DEV unsigned short f2bf(float f) {
  union { float f; unsigned u; } v; v.f = f;
  unsigned u = v.u;
  return (unsigned short)((u + 0x7fffu + ((u >> 16) & 1u)) >> 16);
}
DEV float bf2f(unsigned short s) {
  union { unsigned u; float f; } v; v.u = ((unsigned)s) << 16;
  return v.f;
}

// async global->LDS, 16B per lane. lds must be wave-uniform base; g is per-lane.
DEV void gl_lds16(const unsigned short* g, unsigned short* lds) {
  __builtin_amdgcn_global_load_lds(
      (const __attribute__((address_space(1))) u32*)g,
      (__attribute__((address_space(3))) u32*)lds,
      16, 0, 0);
}

// scheduler-invisible LDS read: compiler sees no LDS access -> no auto vmcnt(0)
// against pending global_load_lds (LDS-DMA). Caller MUST lgkmcnt+sched_barrier.
DEV bf16x8 ds_read128(unsigned byte_off) {
  bf16x8 r;
  asm volatile("ds_read_b128 %0, %1" : "=v"(r) : "v"(byte_off));
  return r;
}

// ---------------- fp32 -> bf16 convert of inputs ----------------
__global__ void k_cvt_x(const float4* __restrict__ x, ushort4* __restrict__ o) {
  int i = blockIdx.x * 256 + threadIdx.x;   // 8388608 float4s
  float4 v = x[i];
  ushort4 r;
  r.x = f2bf(v.x); r.y = f2bf(v.y); r.z = f2bf(v.z); r.w = f2bf(v.w);
  o[i] = r;
}

// ------------- transpose + convert weights: Wt[n][k] = W[k][n] -------------
__global__ void k_transpose(const float* __restrict__ w0, const float* __restrict__ w1,
                            unsigned short* __restrict__ t0, unsigned short* __restrict__ t1) {
  __shared__ float tile[32][33];
  const float* src = blockIdx.z ? w1 : w0;
  unsigned short* dst = blockIdx.z ? t1 : t0;
  int bx = blockIdx.x * 32;  // n (col of W)
  int by = blockIdx.y * 32;  // k (row of W)
  int tx = threadIdx.x & 31, ty = threadIdx.x >> 5;  // 256 threads
#pragma unroll
  for (int r = 0; r < 32; r += 8)
    tile[ty + r][tx] = src[(by + ty + r) * DM + bx + tx];
  __syncthreads();
#pragma unroll
  for (int r = 0; r < 32; r += 8)
    dst[(bx + ty + r) * DM + by + tx] = f2bf(tile[tx][ty + r]);
}

// ---------------- bf16 MFMA GEMM: C = A @ Wt^T + bias ----------------
// 256x256 tile, BK=32, 8 waves (2M x 4N), per-wave 128x64 output.
// 4-deep LDS ring (128 KiB), counted vmcnt(8) + raw s_barrier, inline-asm
// ds_read_b128 (invisible to SIInsertWaitcnts -> counted vmcnt survives),
// both-sides XOR swizzle, 2 phases/tile, setprio around MFMA clusters.
// MODE 0: bf16 out (proj). MODE 1: fp32 out, rows < Mvalid.
template <int MODE>
__global__ __launch_bounds__(512, 2) void k_gemm(const unsigned short* __restrict__ A16,
                                                 const unsigned short* __restrict__ Bt16,
                                                 const float* __restrict__ bias,
                                                 unsigned short* __restrict__ outb,
                                                 float* __restrict__ outf, int Mvalid) {
  // ring: buf b at byte b*32768; A at +0 (256x32), B at +16384 (256x32)
  __shared__ unsigned short lds[4 * 16384];  // 128 KiB

  const int tid = threadIdx.x;
  const int w = tid >> 6, l = tid & 63;
  const int wm = w >> 2, wn = w & 3;         // 2 x 4 wave grid
  const int rr = l & 15, kg = l >> 4;

  // bijective XCD swizzle (m204 general form)
  const int nwg = gridDim.x, orig = blockIdx.x;
  const int q = nwg >> 3, r8 = nwg & 7;
  const int xcd = orig & 7, idx = orig >> 3;
  const int wg = (xcd < r8 ? xcd * (q + 1) : r8 * (q + 1) + (xcd - r8) * q) + idx;
  const int bm = wg >> 2, bn = wg & 3;       // N=1024 -> 4 column tiles
  const int blockM = bm * 256;
  const int blockN = bn * 256;

  f32x4 acc[8][4];
#pragma unroll
  for (int m = 0; m < 8; m++)
#pragma unroll
    for (int n = 0; n < 4; n++) acc[m][n] = (f32x4){0.f, 0.f, 0.f, 0.f};

  // ---- staging: wave w stages rows [w*32, w*32+32) of A and B tiles,
  // 2 chunks of 16 rows; lane -> row +(l>>2), slot l&3 (16B). Global source
  // inverse-swizzled; LDS dest linear (rule 21: both-sides-or-neither).
  const unsigned short* pA[2];
  const unsigned short* pB[2];
#pragma unroll
  for (int cc = 0; cc < 2; cc++) {
    int rp = w * 32 + cc * 16 + (l >> 2);
    int sl = (l & 3) ^ ((rp >> 1) & 3);
    pA[cc] = A16 + (size_t)(blockM + rp) * DM + sl * 8;
    pB[cc] = Bt16 + (size_t)(blockN + rp) * DM + sl * 8;
  }

  // ---- fragment read byte-offsets (swizzled), constant across tiles
  const unsigned ldsbase =
      (unsigned)(size_t)(__attribute__((address_space(3))) unsigned short*)lds;
  unsigned offA[8], offB[4];
#pragma unroll
  for (int mf = 0; mf < 8; mf++) {
    int rrow = wm * 128 + mf * 16 + rr;
    offA[mf] = ldsbase + rrow * 64 + ((kg ^ ((rrow >> 1) & 3)) * 16);
  }
#pragma unroll
  for (int nf = 0; nf < 4; nf++) {
    int rb = wn * 64 + nf * 16 + rr;
    offB[nf] = ldsbase + 16384 + rb * 64 + ((kg ^ ((rb >> 1) & 3)) * 16);
  }

  auto stageA = [&](int t) {
    unsigned short* d = lds + (t & 3) * 16384 + w * 1024;
#pragma unroll
    for (int cc = 0; cc < 2; cc++) gl_lds16(pA[cc] + (size_t)t * 32, d + cc * 512);
  };
  auto stageB = [&](int t) {
    unsigned short* d = lds + (t & 3) * 16384 + 8192 + w * 1024;
#pragma unroll
    for (int cc = 0; cc < 2; cc++) gl_lds16(pB[cc] + (size_t)t * 32, d + cc * 512);
  };

  // prologue: stage tiles 0,1,2 (12 loads in flight per wave)
  stageA(0); stageB(0);
  stageA(1); stageB(1);
  stageA(2); stageB(2);

  for (int t = 0; t < NT; ++t) {
    // counted wait: wave's own 4 loads of tile t confirmed; up to 8 (tiles
    // t+1,t+2) stay in flight. Barrier after => ALL waves' tile-t data landed.
    if (t < NT - 2)       asm volatile("s_waitcnt vmcnt(8)" ::: "memory");
    else if (t == NT - 2) asm volatile("s_waitcnt vmcnt(4)" ::: "memory");
    else                  asm volatile("s_waitcnt vmcnt(0)" ::: "memory");
    __builtin_amdgcn_s_barrier();

    const unsigned bufoff = (unsigned)((t & 3) * 32768);
    const bool do_stage = (t + 3 < NT);

    // ---- phase 0: m-frags 0..3 x all 4 n-frags (16 MFMA)
    bf16x8 bq[4], aq[4];
#pragma unroll
    for (int nf = 0; nf < 4; nf++) bq[nf] = ds_read128(bufoff + offB[nf]);
#pragma unroll
    for (int mf = 0; mf < 4; mf++) aq[mf] = ds_read128(bufoff + offA[mf]);
    if (do_stage) stageA(t + 3);           // issue next-tile loads under the wait
    asm volatile("s_waitcnt lgkmcnt(0)" ::: "memory");
    __builtin_amdgcn_sched_barrier(0);     // rule 18: keep MFMA below the wait
    __builtin_amdgcn_s_setprio(1);
#pragma unroll
    for (int mf = 0; mf < 4; mf++)
#pragma unroll
      for (int nf = 0; nf < 4; nf++)
        acc[mf][nf] = __builtin_amdgcn_mfma_f32_16x16x32_bf16(aq[mf], bq[nf], acc[mf][nf], 0, 0, 0);
    __builtin_amdgcn_s_setprio(0);
    __builtin_amdgcn_s_barrier();

    // ---- phase 1: m-frags 4..7 (B frags resident)
#pragma unroll
    for (int mf = 0; mf < 4; mf++) aq[mf] = ds_read128(bufoff + offA[4 + mf]);
    if (do_stage) stageB(t + 3);
    asm volatile("s_waitcnt lgkmcnt(0)" ::: "memory");
    __builtin_amdgcn_sched_barrier(0);
    __builtin_amdgcn_s_setprio(1);
#pragma unroll
    for (int mf = 0; mf < 4; mf++)
#pragma unroll
      for (int nf = 0; nf < 4; nf++)
        acc[4 + mf][nf] = __builtin_amdgcn_mfma_f32_16x16x32_bf16(aq[mf], bq[nf], acc[4 + mf][nf], 0, 0, 0);
    __builtin_amdgcn_s_setprio(0);
    // loop-top vmcnt+barrier of tile t+1 separates these reads (complete at
    // lgkmcnt above) from stage writes into buf[(t+4)&3] issued next iter.
  }

  // epilogue: C/D mapping col=lane&15, row=(lane>>4)*4+j  [m89-verified]
#pragma unroll
  for (int nf = 0; nf < 4; nf++) {
    int col = blockN + wn * 64 + nf * 16 + (l & 15);
    float bv = bias[col];
#pragma unroll
    for (int mf = 0; mf < 8; mf++) {
      int row = blockM + wm * 128 + mf * 16 + (l >> 4) * 4;
#pragma unroll
      for (int j = 0; j < 4; j++) {
        float v = acc[mf][nf][j] + bv;
        if (MODE == 0) {
          outb[(size_t)(row + j) * DM + col] = f2bf(v);
        } else {
          if (row + j < Mvalid) outf[(size_t)(row + j) * DM + col] = v;
        }
      }
    }
  }
}

// ---------------- scan phase A: per-chunk local (zero-init) end state ----------------
__global__ void k_scan_partial(const unsigned short* __restrict__ proj,
                               const float* __restrict__ logit,
                               const float* __restrict__ z0,
                               float* __restrict__ chunkend) {
  int b = blockIdx.x >> 6, c = blockIdx.x & 63;
  int ch = threadIdx.x;  // 1024 channels = h*64+d
  float a = 1.f / (1.f + expf(-logit[ch >> 6]));
  int t0 = c * CL;
  const unsigned short* p = proj + (size_t)(b * T + t0) * DM + ch;
  float pprev = (t0 == 0) ? z0[ch] : bf2f(p[-DM]);
  float s = 0.f;
  for (int j = 0; j < CL; j++) {
    float pv = bf2f(p[(size_t)j * DM]);
    s = a * s + (1.f - a) * (pv - pprev);
    pprev = pv;
  }
  chunkend[(b * NCH + c) * DM + ch] = s;
}

// ---------------- scan phase B: serial cross-chunk combine ----------------
__global__ void k_scan_combine(const float* __restrict__ chunkend,
                               const float* __restrict__ logit,
                               const float* __restrict__ v0,
                               float* __restrict__ enter) {
  int b = blockIdx.x;
  int ch = threadIdx.x;
  float a = 1.f / (1.f + expf(-logit[ch >> 6]));
  float a2 = a * a, a4 = a2 * a2, a8 = a4 * a4, a16 = a8 * a8, a32 = a16 * a16;
  float aL = a32 * a32;  // a^64
  float e = v0[ch];      // s_{-1}
  enter[(b * NCH + 0) * DM + ch] = e;
  for (int c = 1; c < NCH; c++) {
    e = aL * e + chunkend[(b * NCH + c - 1) * DM + ch];
    enter[(b * NCH + c) * DM + ch] = e;
  }
}

// ---------------- scan phase C: final scan with entry states, write S (bf16) ----------------
__global__ void k_scan_final(const unsigned short* __restrict__ proj,
                             const float* __restrict__ logit,
                             const float* __restrict__ z0,
                             const float* __restrict__ v0,
                             const float* __restrict__ enter,
                             unsigned short* __restrict__ S) {
  int b = blockIdx.x >> 6, c = blockIdx.x & 63;
  int ch = threadIdx.x;
  float a = 1.f / (1.f + expf(-logit[ch >> 6]));
  int t0 = c * CL;
  const unsigned short* p = proj + (size_t)(b * T + t0) * DM + ch;
  unsigned short* so = S + (size_t)(b * (T + 1) + t0 + 1) * DM + ch;
  float pprev = (t0 == 0) ? z0[ch] : bf2f(p[-DM]);
  float s = enter[(b * NCH + c) * DM + ch];
  if (c == 0) S[(size_t)b * (T + 1) * DM + ch] = f2bf(v0[ch]);  // row 0 = v0
  for (int j = 0; j < CL; j++) {
    float pv = bf2f(p[(size_t)j * DM]);
    s = a * s + (1.f - a) * (pv - pprev);
    pprev = pv;
    so[(size_t)j * DM] = f2bf(s);
  }
}

// zero the padded S rows [M2, M2P) so GEMM2 staging reads are benign
__global__ void k_pad(unsigned short* __restrict__ S) {
  int i = blockIdx.x * 256 + threadIdx.x;  // 248*1024 = 253952 elements
  if (i < (M2P - M2) * DM) S[(size_t)M2 * DM + i] = 0;
}

extern "C" void kernel_launch(void* const* d_in, const int* in_sizes, int n_in,
                              void* d_out, int out_size, void* d_ws, size_t ws_size,
                              hipStream_t stream) {
  const float* inputs = (const float*)d_in[0];
  const float* z0     = (const float*)d_in[1];
  const float* W_in   = (const float*)d_in[2];
  const float* b_in   = (const float*)d_in[3];
  const float* W_out  = (const float*)d_in[4];
  const float* b_out  = (const float*)d_in[5];
  const float* slogit = (const float*)d_in[6];
  const float* v0     = (const float*)d_in[7];
  float* out = (float*)d_out;

  char* ws = (char*)d_ws;
  unsigned short* X16   = (unsigned short*)(ws);                    // 67,108,864 B
  unsigned short* P16   = (unsigned short*)(ws + 67108864);         // 67,108,864 B
  unsigned short* S16   = (unsigned short*)(ws + 134217728);        // 67,633,152 B (33024 rows)
  unsigned short* WTin  = (unsigned short*)(ws + 201850880);        // 2,097,152 B
  unsigned short* WTout = (unsigned short*)(ws + 203948032);        // 2,097,152 B
  float* chunkend       = (float*)(ws + 206045184);                 // 2,097,152 B
  float* enter          = (float*)(ws + 208142336);                 // 2,097,152 B

  // 1. convert inputs to bf16
  k_cvt_x<<<32768, 256, 0, stream>>>((const float4*)inputs, (ushort4*)X16);
  // 2. transpose+convert both weights
  k_transpose<<<dim3(32, 32, 2), 256, 0, stream>>>(W_in, W_out, WTin, WTout);
  // 3. GEMM1: proj = inputs @ W_in + b_in   (bf16 out), 128x4 = 512 wgs
  k_gemm<0><<<dim3((M1 / 256) * 4), 512, 0, stream>>>(X16, WTin, b_in, P16, nullptr, M1);
  // 4. scan: temporal diff + exponential smoothing
  k_scan_partial<<<dim3(BATCH * NCH), 1024, 0, stream>>>(P16, slogit, z0, chunkend);
  k_scan_combine<<<dim3(BATCH), 1024, 0, stream>>>(chunkend, slogit, v0, enter);
  k_scan_final<<<dim3(BATCH * NCH), 1024, 0, stream>>>(P16, slogit, z0, v0, enter, S16);
  k_pad<<<dim3(992), 256, 0, stream>>>(S16);
  // 5. GEMM2: out = S @ W_out + b_out  (fp32 out, 32776 valid rows of 33024), 129x4 = 516 wgs
  k_gemm<1><<<dim3((M2P / 256) * 4), 512, 0, stream>>>(S16, WTout, b_out, nullptr, out, M2);
}

// Round 5
// 291.649 us; speedup vs baseline: 1.0439x; 1.0439x over previous
//
#include <hip/hip_runtime.h>
#include <hip/hip_bf16.h>
#include <stdint.h>

#define DEV static __device__ __forceinline__

typedef __attribute__((ext_vector_type(8))) short bf16x8;
typedef __attribute__((ext_vector_type(4))) float f32x4;
typedef unsigned int u32;

static constexpr int T = 4096;
static constexpr int BATCH = 8;
static constexpr int DM = 1024;            // d_model = nhead*d_head
static constexpr int M1 = BATCH * T;       // 32768 rows into GEMM1
static constexpr int M2 = BATCH * (T + 1); // 32776 rows into GEMM2
static constexpr int M2P = 129 * 256;      // 33024 padded rows for S (256-tile)
static constexpr int NCH = 64;             // time chunks for scan
static constexpr int CL = T / NCH;         // 64 steps per chunk
static constexpr int NT = 16;              // K tiles (BK=64, K=1024)

DEV unsigned short f2bf(float f) {
  union { float f; unsigned u; } v; v.f = f;
  unsigned u = v.u;
  return (unsigned short)((u + 0x7fffu + ((u >> 16) & 1u)) >> 16);
}
DEV float bf2f(unsigned short s) {
  union { unsigned u; float f; } v; v.u = ((unsigned)s) << 16;
  return v.f;
}

// async global->LDS, 16B per lane. lds dest must be wave-uniform; g is per-lane.
DEV void gl_lds16(const unsigned short* g, unsigned short* lds) {
  __builtin_amdgcn_global_load_lds(
      (const __attribute__((address_space(1))) u32*)g,
      (__attribute__((address_space(3))) u32*)lds,
      16, 0, 0);
}

// scheduler-invisible LDS read (rule 18: caller must lgkmcnt(0)+sched_barrier(0))
DEV bf16x8 ds_read128(unsigned byte_off) {
  bf16x8 r;
  asm volatile("ds_read_b128 %0, %1" : "=v"(r) : "v"(byte_off));
  return r;
}

// ---------------- fp32 -> bf16 convert of inputs ----------------
__global__ void k_cvt_x(const float4* __restrict__ x, ushort4* __restrict__ o) {
  int i = blockIdx.x * 256 + threadIdx.x;   // 8388608 float4s
  float4 v = x[i];
  ushort4 r;
  r.x = f2bf(v.x); r.y = f2bf(v.y); r.z = f2bf(v.z); r.w = f2bf(v.w);
  o[i] = r;
}

// ------------- transpose + convert weights: Wt[n][k] = W[k][n] -------------
__global__ void k_transpose(const float* __restrict__ w0, const float* __restrict__ w1,
                            unsigned short* __restrict__ t0, unsigned short* __restrict__ t1) {
  __shared__ float tile[32][33];
  const float* src = blockIdx.z ? w1 : w0;
  unsigned short* dst = blockIdx.z ? t1 : t0;
  int bx = blockIdx.x * 32;  // n (col of W)
  int by = blockIdx.y * 32;  // k (row of W)
  int tx = threadIdx.x & 31, ty = threadIdx.x >> 5;  // 256 threads
#pragma unroll
  for (int r = 0; r < 32; r += 8)
    tile[ty + r][tx] = src[(by + ty + r) * DM + bx + tx];
  __syncthreads();
#pragma unroll
  for (int r = 0; r < 32; r += 8)
    dst[(bx + ty + r) * DM + by + tx] = f2bf(tile[tx][ty + r]);
}

// ---------------- bf16 MFMA GEMM: C = A @ Wt^T + bias ----------------
// m201-style derived-waits port: 256x256 tile, BK=64, 8 waves (2M x 4N),
// 2-deep LDS dbuf (128 KiB), 4 phases/K-tile each {ds_read, stage quarter(s),
// lgkm0, 16 MFMA, barrier}, ONE vmcnt(6) per K-tile (never drains mid-loop).
// Quarter-stage: 1 gl_lds x 8 waves = 64 rows x 64k. Tile t's 8 loads issued
// {6 @ ph3 of t-2, 2 @ ph0 of t-1} -> oldest-8 at tile-t top = vmcnt(6).
// MODE 0: bf16 out (proj). MODE 1: fp32 out, rows < Mvalid.
template <int MODE>
__global__ __launch_bounds__(512, 2) void k_gemm(const unsigned short* __restrict__ A16,
                                                 const unsigned short* __restrict__ Bt16,
                                                 const float* __restrict__ bias,
                                                 unsigned short* __restrict__ outb,
                                                 float* __restrict__ outf, int Mvalid) {
  // buf c at c*32768 elems (65536 B); A at +0 (256x64), B at +16384 elems
  __shared__ unsigned short lds[2 * 32768];  // 128 KiB

  const int tid = threadIdx.x;
  const int w = tid >> 6, l = tid & 63;
  const int wm = w >> 2, wn = w & 3;         // 2 x 4 wave grid
  const int rr = l & 15, kg = l >> 4;

  // bijective XCD swizzle (m204 general form)
  const int nwg = gridDim.x, orig = blockIdx.x;
  const int q8 = nwg >> 3, r8 = nwg & 7;
  const int xcd = orig & 7, idx = orig >> 3;
  const int wg = (xcd < r8 ? xcd * (q8 + 1) : r8 * (q8 + 1) + (xcd - r8) * q8) + idx;
  const int bm = wg >> 2, bn = wg & 3;       // N=1024 -> 4 column tiles
  const int blockM = bm * 256;
  const int blockN = bn * 256;

  f32x4 acc[8][4];
#pragma unroll
  for (int m = 0; m < 8; m++)
#pragma unroll
    for (int n = 0; n < 4; n++) acc[m][n] = (f32x4){0.f, 0.f, 0.f, 0.f};

  // ---- staging: quarter q = 64 rows; wave w covers rows q*64+w*8..+8.
  // LDS dest linear; global k-slot inverse-swizzled: s = (l&7)^((l>>3)&7)
  // (row&7 == (l>>3)&7 since q*64+w*8 == 0 mod 8).  [rule 21 both-sides]
  const int srow = w * 8 + (l >> 3);
  const int sslot = (l & 7) ^ ((l >> 3) & 7);
  const unsigned short* pA = A16 + (size_t)(blockM + srow) * DM + sslot * 8;
  const unsigned short* pB = Bt16 + (size_t)(blockN + srow) * DM + sslot * 8;

  auto stage = [&](int t, int q, bool isB) {
    unsigned short* d = lds + (t & 1) * 32768 + (isB ? 16384 : 0) + q * 4096 + w * 512;
    gl_lds16((isB ? pB : pA) + (size_t)q * 64 * DM + (size_t)t * 64, d);
  };

  // ---- fragment read byte-offsets: row r, k-slot s=h*4+kg, swizzled s^(r&7)
  const unsigned ldsbase =
      (unsigned)(size_t)(__attribute__((address_space(3))) unsigned short*)lds;
  unsigned offA[2][8], offB[2][4];
#pragma unroll
  for (int h = 0; h < 2; h++) {
#pragma unroll
    for (int mf = 0; mf < 8; mf++) {
      int r = wm * 128 + mf * 16 + rr;
      offA[h][mf] = ldsbase + r * 128 + ((((h << 2) | kg) ^ (r & 7)) << 4);
    }
#pragma unroll
    for (int nf = 0; nf < 4; nf++) {
      int r = wn * 64 + nf * 16 + rr;
      offB[h][nf] = ldsbase + 32768 + r * 128 + ((((h << 2) | kg) ^ (r & 7)) << 4);
    }
  }

  // prologue: all 8 quarters of tile 0, then 6 of tile 1 (A-Q0,Q2 + B-all)
#pragma unroll
  for (int q = 0; q < 4; q++) { stage(0, q, false); stage(0, q, true); }
  stage(1, 0, false); stage(1, 2, false);
#pragma unroll
  for (int q = 0; q < 4; q++) stage(1, q, true);

  for (int t = 0; t < NT; ++t) {
    // ONE counted wait per K-tile: tile t's 8 loads are the oldest; 6 of t+1
    // (issued ph3 of t-1) remain in flight across the barrier.
    if (t < NT - 1) asm volatile("s_waitcnt vmcnt(6)" ::: "memory");
    else            asm volatile("s_waitcnt vmcnt(0)" ::: "memory");
    __builtin_amdgcn_s_barrier();

    const unsigned bo = (unsigned)((t & 1) * 65536);
    bf16x8 aq[4], bq0[4], bq1[4];

    // ---- ph0: B k0 + A m0-3 k0 reads; stage A-Q1,Q3(t+1) -> other buffer
#pragma unroll
    for (int nf = 0; nf < 4; nf++) bq0[nf] = ds_read128(bo + offB[0][nf]);
#pragma unroll
    for (int mf = 0; mf < 4; mf++) aq[mf] = ds_read128(bo + offA[0][mf]);
    if (t + 1 < NT) { stage(t + 1, 1, false); stage(t + 1, 3, false); }
    asm volatile("s_waitcnt lgkmcnt(0)" ::: "memory");
    __builtin_amdgcn_sched_barrier(0);
    __builtin_amdgcn_s_setprio(1);
#pragma unroll
    for (int mf = 0; mf < 4; mf++)
#pragma unroll
      for (int nf = 0; nf < 4; nf++)
        acc[mf][nf] = __builtin_amdgcn_mfma_f32_16x16x32_bf16(aq[mf], bq0[nf], acc[mf][nf], 0, 0, 0);
    __builtin_amdgcn_s_setprio(0);
    __builtin_amdgcn_s_barrier();

    // ---- ph1: A m4-7 k0
#pragma unroll
    for (int mf = 0; mf < 4; mf++) aq[mf] = ds_read128(bo + offA[0][4 + mf]);
    asm volatile("s_waitcnt lgkmcnt(0)" ::: "memory");
    __builtin_amdgcn_sched_barrier(0);
    __builtin_amdgcn_s_setprio(1);
#pragma unroll
    for (int mf = 0; mf < 4; mf++)
#pragma unroll
      for (int nf = 0; nf < 4; nf++)
        acc[4 + mf][nf] = __builtin_amdgcn_mfma_f32_16x16x32_bf16(aq[mf], bq0[nf], acc[4 + mf][nf], 0, 0, 0);
    __builtin_amdgcn_s_setprio(0);
    __builtin_amdgcn_s_barrier();

    // ---- ph2: B k1 + A m0-3 k1 (these regions get re-staged in ph3)
#pragma unroll
    for (int nf = 0; nf < 4; nf++) bq1[nf] = ds_read128(bo + offB[1][nf]);
#pragma unroll
    for (int mf = 0; mf < 4; mf++) aq[mf] = ds_read128(bo + offA[1][mf]);
    asm volatile("s_waitcnt lgkmcnt(0)" ::: "memory");
    __builtin_amdgcn_sched_barrier(0);
    __builtin_amdgcn_s_setprio(1);
#pragma unroll
    for (int mf = 0; mf < 4; mf++)
#pragma unroll
      for (int nf = 0; nf < 4; nf++)
        acc[mf][nf] = __builtin_amdgcn_mfma_f32_16x16x32_bf16(aq[mf], bq1[nf], acc[mf][nf], 0, 0, 0);
    __builtin_amdgcn_s_setprio(0);
    __builtin_amdgcn_s_barrier();  // REQUIRED: ph3 stages into regions ph2 read

    // ---- ph3: A m4-7 k1; stage A-Q0,Q2 + B-all of t+2 into THIS buffer
#pragma unroll
    for (int mf = 0; mf < 4; mf++) aq[mf] = ds_read128(bo + offA[1][4 + mf]);
    if (t + 2 < NT) {
      stage(t + 2, 0, false); stage(t + 2, 2, false);
#pragma unroll
      for (int q = 0; q < 4; q++) stage(t + 2, q, true);
    }
    asm volatile("s_waitcnt lgkmcnt(0)" ::: "memory");
    __builtin_amdgcn_sched_barrier(0);
    __builtin_amdgcn_s_setprio(1);
#pragma unroll
    for (int mf = 0; mf < 4; mf++)
#pragma unroll
      for (int nf = 0; nf < 4; nf++)
        acc[4 + mf][nf] = __builtin_amdgcn_mfma_f32_16x16x32_bf16(aq[mf], bq1[nf], acc[4 + mf][nf], 0, 0, 0);
    __builtin_amdgcn_s_setprio(0);
    // no trailing barrier: tile-top barrier of t+1 follows (reads already
    // complete at lgkmcnt above; stage targets checked against t+1's readers)
  }

  // epilogue: C/D mapping col=lane&15, row=(lane>>4)*4+j  [m89-verified]
#pragma unroll
  for (int nf = 0; nf < 4; nf++) {
    int col = blockN + wn * 64 + nf * 16 + (l & 15);
    float bv = bias[col];
#pragma unroll
    for (int mf = 0; mf < 8; mf++) {
      int row = blockM + wm * 128 + mf * 16 + (l >> 4) * 4;
#pragma unroll
      for (int j = 0; j < 4; j++) {
        float v = acc[mf][nf][j] + bv;
        if (MODE == 0) {
          outb[(size_t)(row + j) * DM + col] = f2bf(v);
        } else {
          if (row + j < Mvalid) outf[(size_t)(row + j) * DM + col] = v;
        }
      }
    }
  }
}

// ---------------- scan phase A: per-chunk local (zero-init) end state ----------------
__global__ void k_scan_partial(const unsigned short* __restrict__ proj,
                               const float* __restrict__ logit,
                               const float* __restrict__ z0,
                               float* __restrict__ chunkend) {
  int b = blockIdx.x >> 6, c = blockIdx.x & 63;
  int ch = threadIdx.x;  // 1024 channels = h*64+d
  float a = 1.f / (1.f + expf(-logit[ch >> 6]));
  int t0 = c * CL;
  const unsigned short* p = proj + (size_t)(b * T + t0) * DM + ch;
  float pprev = (t0 == 0) ? z0[ch] : bf2f(p[-DM]);
  float s = 0.f;
  for (int j = 0; j < CL; j++) {
    float pv = bf2f(p[(size_t)j * DM]);
    s = a * s + (1.f - a) * (pv - pprev);
    pprev = pv;
  }
  chunkend[(b * NCH + c) * DM + ch] = s;
}

// ---------------- scan phase B: serial cross-chunk combine ----------------
__global__ void k_scan_combine(const float* __restrict__ chunkend,
                               const float* __restrict__ logit,
                               const float* __restrict__ v0,
                               float* __restrict__ enter) {
  int b = blockIdx.x;
  int ch = threadIdx.x;
  float a = 1.f / (1.f + expf(-logit[ch >> 6]));
  float a2 = a * a, a4 = a2 * a2, a8 = a4 * a4, a16 = a8 * a8, a32 = a16 * a16;
  float aL = a32 * a32;  // a^64
  float e = v0[ch];      // s_{-1}
  enter[(b * NCH + 0) * DM + ch] = e;
  for (int c = 1; c < NCH; c++) {
    e = aL * e + chunkend[(b * NCH + c - 1) * DM + ch];
    enter[(b * NCH + c) * DM + ch] = e;
  }
}

// ---------------- scan phase C: final scan with entry states, write S (bf16) ----------------
__global__ void k_scan_final(const unsigned short* __restrict__ proj,
                             const float* __restrict__ logit,
                             const float* __restrict__ z0,
                             const float* __restrict__ v0,
                             const float* __restrict__ enter,
                             unsigned short* __restrict__ S) {
  int b = blockIdx.x >> 6, c = blockIdx.x & 63;
  int ch = threadIdx.x;
  float a = 1.f / (1.f + expf(-logit[ch >> 6]));
  int t0 = c * CL;
  const unsigned short* p = proj + (size_t)(b * T + t0) * DM + ch;
  unsigned short* so = S + (size_t)(b * (T + 1) + t0 + 1) * DM + ch;
  float pprev = (t0 == 0) ? z0[ch] : bf2f(p[-DM]);
  float s = enter[(b * NCH + c) * DM + ch];
  if (c == 0) S[(size_t)b * (T + 1) * DM + ch] = f2bf(v0[ch]);  // row 0 = v0
  for (int j = 0; j < CL; j++) {
    float pv = bf2f(p[(size_t)j * DM]);
    s = a * s + (1.f - a) * (pv - pprev);
    pprev = pv;
    so[(size_t)j * DM] = f2bf(s);
  }
}

// zero the padded S rows [M2, M2P) so GEMM2 staging reads are benign
__global__ void k_pad(unsigned short* __restrict__ S) {
  int i = blockIdx.x * 256 + threadIdx.x;  // 248*1024 = 253952 elements
  if (i < (M2P - M2) * DM) S[(size_t)M2 * DM + i] = 0;
}

extern "C" void kernel_launch(void* const* d_in, const int* in_sizes, int n_in,
                              void* d_out, int out_size, void* d_ws, size_t ws_size,
                              hipStream_t stream) {
  const float* inputs = (const float*)d_in[0];
  const float* z0     = (const float*)d_in[1];
  const float* W_in   = (const float*)d_in[2];
  const float* b_in   = (const float*)d_in[3];
  const float* W_out  = (const float*)d_in[4];
  const float* b_out  = (const float*)d_in[5];
  const float* slogit = (const float*)d_in[6];
  const float* v0     = (const float*)d_in[7];
  float* out = (float*)d_out;

  char* ws = (char*)d_ws;
  unsigned short* X16   = (unsigned short*)(ws);                    // 67,108,864 B
  unsigned short* P16   = (unsigned short*)(ws + 67108864);         // 67,108,864 B
  unsigned short* S16   = (unsigned short*)(ws + 134217728);        // 67,633,152 B (33024 rows)
  unsigned short* WTin  = (unsigned short*)(ws + 201850880);        // 2,097,152 B
  unsigned short* WTout = (unsigned short*)(ws + 203948032);        // 2,097,152 B
  float* chunkend       = (float*)(ws + 206045184);                 // 2,097,152 B
  float* enter          = (float*)(ws + 208142336);                 // 2,097,152 B

  // 1. convert inputs to bf16
  k_cvt_x<<<32768, 256, 0, stream>>>((const float4*)inputs, (ushort4*)X16);
  // 2. transpose+convert both weights
  k_transpose<<<dim3(32, 32, 2), 256, 0, stream>>>(W_in, W_out, WTin, WTout);
  // 3. GEMM1: proj = inputs @ W_in + b_in   (bf16 out), 128x4 = 512 wgs
  k_gemm<0><<<dim3((M1 / 256) * 4), 512, 0, stream>>>(X16, WTin, b_in, P16, nullptr, M1);
  // 4. scan: temporal diff + exponential smoothing
  k_scan_partial<<<dim3(BATCH * NCH), 1024, 0, stream>>>(P16, slogit, z0, chunkend);
  k_scan_combine<<<dim3(BATCH), 1024, 0, stream>>>(chunkend, slogit, v0, enter);
  k_scan_final<<<dim3(BATCH * NCH), 1024, 0, stream>>>(P16, slogit, z0, v0, enter, S16);
  k_pad<<<dim3(992), 256, 0, stream>>>(S16);
  // 5. GEMM2: out = S @ W_out + b_out  (fp32 out, 32776 valid rows of 33024), 129x4 = 516 wgs
  k_gemm<1><<<dim3((M2P / 256) * 4), 512, 0, stream>>>(S16, WTout, b_out, nullptr, out, M2);
}